// Round 11
// baseline (79.841 us; speedup 1.0000x reference)
//
#include <hip/hip_runtime.h>
#include <math.h>

#define INFBITS 0x7F800000u
#define TCH 128          // chamfer LDS tile (R9-best)
#define PTS 8            // query points per thread (R9-best)
#define DICE_BLOCKS 512

// ---------- block-wide sum (blockDim.x == 256, 4 waves) ----------
__device__ __forceinline__ float block_sum256(float v) {
#pragma unroll
    for (int o = 32; o > 0; o >>= 1) v += __shfl_down(v, o, 64);
    __shared__ float sb[4];
    if ((threadIdx.x & 63) == 0) sb[threadIdx.x >> 6] = v;
    __syncthreads();
    float r = sb[0] + sb[1] + sb[2] + sb[3];
    __syncthreads();
    return r;
}

// ---------- single fused kernel ----------
// blocks [0, DICE_BLOCKS)   : dice grid-stride partial sums
// blocks [DICE_BLOCKS, ...) : chamfer partial mins -> atomicMin into m0/m1
// ALL blocks then arrive at `counter`; the last block reduces mins (via
// atomic reads, coherent with the atomicMin writes) + dice partials and
// writes the scalar. m0/m1/counter are pre-set to 0xFF by a memset node:
// mins start at 0xFFFFFFFF (> any valid d2 bits), counter starts at
// 0xFFFFFFFF so the k-th arrival's returned `old` is k-2 (wrapped) and the
// last of nblk arrivals uniquely sees old == nblk-2.
__global__ void __launch_bounds__(256) fused_all(
        const float4* __restrict__ p4, const float4* __restrict__ t4, int n4,
        float* __restrict__ inter_p, float* __restrict__ uni_p,
        const float2* __restrict__ P, const float2* __restrict__ T,
        int N, int M,
        unsigned int* __restrict__ m0, unsigned int* __restrict__ m1,
        unsigned int* __restrict__ counter,
        int chm, int gxp, int nblk, float* __restrict__ out) {
    int bid = blockIdx.x;
    int t   = threadIdx.x;

    if (bid < DICE_BLOCKS) {
        // ---- dice partial sums ----
        float inter = 0.f, uni = 0.f;
#pragma unroll 2
        for (int i = bid * 256 + t; i < n4; i += DICE_BLOCKS * 256) {
            float4 p = p4[i];
            float4 tt = t4[i];
            float s;
            s = __fdividef(1.f, 1.f + __expf(-p.x)); inter = fmaf(s, tt.x, inter); uni += s + tt.x;
            s = __fdividef(1.f, 1.f + __expf(-p.y)); inter = fmaf(s, tt.y, inter); uni += s + tt.y;
            s = __fdividef(1.f, 1.f + __expf(-p.z)); inter = fmaf(s, tt.z, inter); uni += s + tt.z;
            s = __fdividef(1.f, 1.f + __expf(-p.w)); inter = fmaf(s, tt.w, inter); uni += s + tt.w;
        }
        float bi = block_sum256(inter);
        float bu = block_sum256(uni);
        if (t == 0) { inter_p[bid] = bi; uni_p[bid] = bu; }
    } else {
        // ---- chamfer partial mins (R9-identical inner loop) ----
        int cb      = bid - DICE_BLOCKS;
        int per_dir = gxp * chm;
        int dir     = cb / per_dir;
        int rem     = cb - dir * per_dir;
        int cy      = rem / gxp;          // target chunk
        int cx      = rem - cy * gxp;     // query-point group
        const float2* A = dir ? T : P;
        const float2* B = dir ? P : T;
        int nA = dir ? M : N;
        int nB = dir ? N : M;
        unsigned int* marr = dir ? m1 : m0;

        int tb = cy * TCH;
        if (tb < nB) {                    // uniform per block; OOB blocks just arrive
            __shared__ __align__(16) float2 xy[TCH];
            if (t < TCH) {
                float2 b = make_float2(1e18f, 1e18f);   // pad never wins the min
                if (tb + t < nB) b = B[tb + t];
                xy[t] = b;
            }
            __syncthreads();

            int abase = cx * (PTS * 256);
            float nx[PTS], ny[PTS], mn[PTS];
#pragma unroll
            for (int i = 0; i < PTS; ++i) {
                int p = abase + i * 256 + t;
                nx[i] = 0.f; ny[i] = 0.f;
                mn[i] = __uint_as_float(INFBITS);
                if (p < nA) {
                    float2 a = A[p];
                    nx[i] = -2.f * a.x;
                    ny[i] = -2.f * a.y;
                }
            }

#pragma unroll 4
            for (int j = 0; j < TCH; j += 2) {
                float4 q = *(const float4*)&xy[j];      // {b0.x,b0.y,b1.x,b1.y}
                float s20 = fmaf(q.x, q.x, q.y * q.y);
                float s21 = fmaf(q.z, q.z, q.w * q.w);
#pragma unroll
                for (int i = 0; i < PTS; ++i)
                    mn[i] = fminf(mn[i], fmaf(nx[i], q.x, fmaf(ny[i], q.y, s20)));
#pragma unroll
                for (int i = 0; i < PTS; ++i)
                    mn[i] = fminf(mn[i], fmaf(nx[i], q.z, fmaf(ny[i], q.w, s21)));
            }

            // epilogue: add back ||a||^2 (recomputed from nx,ny: 0 extra VGPR),
            // clamp >=0 so float bit order == uint order, then atomicMin.
#pragma unroll
            for (int i = 0; i < PTS; ++i) {
                int p = abase + i * 256 + t;
                if (p < nA) {
                    float sa  = 0.25f * fmaf(nx[i], nx[i], ny[i] * ny[i]);
                    float key = fmaxf(mn[i] + sa, 0.f);
                    atomicMin(marr + p, __float_as_uint(key));
                }
            }
            __threadfence();   // drain this wave's atomics before arrival
        }
    }

    // ---- arrive; last block finalizes ----
    __syncthreads();
    __shared__ int is_last;
    if (t == 0) {
        __threadfence();
        unsigned int old = atomicAdd(counter, 1u);
        is_last = (old == (unsigned)(nblk - 2));
    }
    __syncthreads();
    if (!is_last) return;

    float c0 = 0.f, c1 = 0.f, inter = 0.f, uni = 0.f;
    for (int i = t; i < N; i += 256)
        c0 += __uint_as_float(atomicMin(m0 + i, 0xFFFFFFFFu));   // atomic read
    for (int i = t; i < M; i += 256)
        c1 += __uint_as_float(atomicMin(m1 + i, 0xFFFFFFFFu));
    const volatile float* vi = inter_p;
    const volatile float* vu = uni_p;
    for (int i = t; i < DICE_BLOCKS; i += 256) { inter += vi[i]; uni += vu[i]; }

    float bi  = block_sum256(inter);
    float bu  = block_sum256(uni);
    float bc0 = block_sum256(c0);
    float bc1 = block_sum256(c1);
    if (t == 0) {
        const float SMOOTH = 1e-6f;
        float dice    = (2.f * bi + SMOOTH) / (bu + SMOOTH);
        float chamfer = bc0 / (float)N + bc1 / (float)M;
        out[0] = 0.5f * (1.f - dice) + 0.5f * chamfer;
    }
}

extern "C" void kernel_launch(void* const* d_in, const int* in_sizes, int n_in,
                              void* d_out, int out_size, void* d_ws, size_t ws_size,
                              hipStream_t stream) {
    const float*  pred = (const float*)d_in[0];
    const float*  targ = (const float*)d_in[1];
    const float2* pp   = (const float2*)d_in[2];
    const float2* tp   = (const float2*)d_in[3];
    int n = in_sizes[0];
    int N = in_sizes[2] / 2;
    int M = in_sizes[3] / 2;
    float* out = (float*)d_out;

    int npm = N > M ? N : M;
    int chm = (npm + TCH - 1) / TCH;
    int gxp = (npm + PTS * 256 - 1) / (PTS * 256);
    int cham_blocks = 2 * gxp * chm;
    int nblk = DICE_BLOCKS + cham_blocks;

    // ws layout: [m0 (N) | m1 (M) | counter (1)] <- memset 0xFF each call,
    // then (256-aligned) inter_p[512] | uni_p[512] (rewritten before read).
    char* ws = (char*)d_ws;
    unsigned int* m0      = (unsigned int*)ws;
    unsigned int* m1      = m0 + N;
    unsigned int* counter = m1 + M;
    size_t msz = (size_t)(N + M + 1) * sizeof(unsigned int);
    size_t off = (msz + 255) & ~(size_t)255;
    float* inter_p = (float*)(ws + off);
    float* uni_p   = inter_p + DICE_BLOCKS;

    hipMemsetAsync(ws, 0xFF, msz, stream);

    fused_all<<<nblk, 256, 0, stream>>>(
        (const float4*)pred, (const float4*)targ, n / 4,
        inter_p, uni_p, pp, tp, N, M, m0, m1, counter,
        chm, gxp, nblk, out);
}

// Round 12
// 45.112 us; speedup vs baseline: 1.7698x; 1.7698x over previous
//
#include <hip/hip_runtime.h>
#include <math.h>

#define INFBITS 0x7F800000u
#define TCH 64           // chamfer LDS tile -> 1024 pure-chamfer blocks
#define PTS 8            // query points per thread (R9-best)
#define DICE_BLOCKS 512
#define SCAN_PER_DIR 32  // 8192/256

// ---------- block-wide sum (blockDim.x == 256, 4 waves) ----------
__device__ __forceinline__ float block_sum256(float v) {
#pragma unroll
    for (int o = 32; o > 0; o >>= 1) v += __shfl_down(v, o, 64);
    __shared__ float sb[4];
    if ((threadIdx.x & 63) == 0) sb[threadIdx.x >> 6] = v;
    __syncthreads();
    float r = sb[0] + sb[1] + sb[2] + sb[3];
    __syncthreads();
    return r;
}

// ---------- K1: PURE chamfer partial mins ----------
// R12 theory: in the fused K1, memory-waiting dice waves and VALU-bound
// chamfer waves contended for wave slots / VALU issue; segregating gives
// chamfer 4 homogeneous waves/SIMD. Inner loop is byte-identical to R9.
__global__ void __launch_bounds__(256) cham_partials(
        const float2* __restrict__ P, const float2* __restrict__ T,
        int N, int M, float* __restrict__ pm, int npm, int chm, int gxp,
        unsigned int* __restrict__ counter) {
    int bid = blockIdx.x;
    if (bid == 0 && threadIdx.x == 0) *counter = 0u;   // reset K2's semaphore

    int per_dir = gxp * chm;
    int dir     = bid / per_dir;
    int rem     = bid - dir * per_dir;
    int cy      = rem / gxp;          // target chunk
    int cx      = rem - cy * gxp;     // query-point group
    const float2* A = dir ? T : P;
    const float2* B = dir ? P : T;
    int nA = dir ? M : N;
    int nB = dir ? N : M;

    int tb = cy * TCH;
    if (tb >= nB) return;             // uniform per block

    __shared__ __align__(16) float2 xy[TCH];
    int t = threadIdx.x;
    if (t < TCH) {
        float2 b = make_float2(1e18f, 1e18f);   // pad never wins the min
        if (tb + t < nB) b = B[tb + t];
        xy[t] = b;
    }
    __syncthreads();

    int abase = cx * (PTS * 256);
    float nx[PTS], ny[PTS], mn[PTS];
#pragma unroll
    for (int i = 0; i < PTS; ++i) {
        int p = abase + i * 256 + t;
        nx[i] = 0.f; ny[i] = 0.f;
        mn[i] = __uint_as_float(INFBITS);
        if (p < nA) {
            float2 a = A[p];
            nx[i] = -2.f * a.x;
            ny[i] = -2.f * a.y;
        }
    }

    // one broadcast ds_read_b128 per TWO targets; ||b||^2 recomputed in VALU
#pragma unroll 4
    for (int j = 0; j < TCH; j += 2) {
        float4 q = *(const float4*)&xy[j];            // {b0.x,b0.y,b1.x,b1.y}
        float s20 = fmaf(q.x, q.x, q.y * q.y);
        float s21 = fmaf(q.z, q.z, q.w * q.w);
#pragma unroll
        for (int i = 0; i < PTS; ++i)
            mn[i] = fminf(mn[i], fmaf(nx[i], q.x, fmaf(ny[i], q.y, s20)));
#pragma unroll
        for (int i = 0; i < PTS; ++i)
            mn[i] = fminf(mn[i], fmaf(nx[i], q.z, fmaf(ny[i], q.w, s21)));
    }

    float* dstc = pm + ((size_t)dir * chm + cy) * npm;
#pragma unroll
    for (int i = 0; i < PTS; ++i) {
        int p = abase + i * 256 + t;
        if (p < nA) dstc[p] = mn[i];
    }
}

// ---------- K2: dice + pm-scan + combine ----------
// blocks [0, 64)        : per-point min across chunks + ||a||^2 + block-sum
// blocks [64, 64+512)   : dice grid-stride partial sums
// last arrival          : combine everything, write scalar
__global__ void __launch_bounds__(256) finalize_all(
        const float4* __restrict__ p4, const float4* __restrict__ t4, int n4,
        const float* __restrict__ pm, int npm, int chm,
        int N, int M, int nch0, int nch1,
        const float2* __restrict__ P, const float2* __restrict__ T,
        float* __restrict__ inter_p, float* __restrict__ uni_p,
        float* __restrict__ bsum, unsigned int* __restrict__ counter,
        int nblk, float* __restrict__ out) {
    int bid = blockIdx.x;
    int t   = threadIdx.x;

    if (bid < 2 * SCAN_PER_DIR) {
        // ---- chamfer cross-chunk min scan ----
        int dir = bid / SCAN_PER_DIR;
        int bx  = bid - dir * SCAN_PER_DIR;
        int nA  = dir ? M : N;
        int nch = dir ? nch1 : nch0;
        const float2* A = dir ? T : P;

        int p = bx * 256 + t;
        float v = 0.f;
        if (p < nA) {
            const float* src = pm + (size_t)dir * chm * npm + p;
            float m = __uint_as_float(INFBITS);
#pragma unroll 16
            for (int c = 0; c < nch; ++c) m = fminf(m, src[(size_t)c * npm]);
            float2 a = A[p];
            v = m + fmaf(a.x, a.x, a.y * a.y);   // add the deferred ||a||^2
        }
        float s = block_sum256(v);
        if (t == 0) bsum[bid] = s;
    } else {
        // ---- dice partial sums ----
        int did = bid - 2 * SCAN_PER_DIR;
        float inter = 0.f, uni = 0.f;
#pragma unroll 2
        for (int i = did * 256 + t; i < n4; i += DICE_BLOCKS * 256) {
            float4 p = p4[i];
            float4 tt = t4[i];
            float s;
            s = __fdividef(1.f, 1.f + __expf(-p.x)); inter = fmaf(s, tt.x, inter); uni += s + tt.x;
            s = __fdividef(1.f, 1.f + __expf(-p.y)); inter = fmaf(s, tt.y, inter); uni += s + tt.y;
            s = __fdividef(1.f, 1.f + __expf(-p.z)); inter = fmaf(s, tt.z, inter); uni += s + tt.z;
            s = __fdividef(1.f, 1.f + __expf(-p.w)); inter = fmaf(s, tt.w, inter); uni += s + tt.w;
        }
        float bi = block_sum256(inter);
        float bu = block_sum256(uni);
        if (t == 0) { inter_p[did] = bi; uni_p[did] = bu; }
    }

    // ---- arrive; last block combines ----
    __shared__ int is_last;
    if (t == 0) {
        __threadfence();
        unsigned int old = atomicAdd(counter, 1u);
        is_last = (old == (unsigned)(nblk - 1));
    }
    __syncthreads();
    if (!is_last) return;
    __threadfence();

    float inter = 0.f, uni = 0.f, c0 = 0.f, c1 = 0.f;
    const volatile float* vi = inter_p;
    const volatile float* vu = uni_p;
    for (int i = t; i < DICE_BLOCKS; i += 256) { inter += vi[i]; uni += vu[i]; }
    const volatile float* vb = bsum;
    if (t < SCAN_PER_DIR)            c0 = vb[t];
    else if (t < 2 * SCAN_PER_DIR)   c1 = vb[t];

    float bi  = block_sum256(inter);
    float bu  = block_sum256(uni);
    float bc0 = block_sum256(c0);
    float bc1 = block_sum256(c1);
    if (t == 0) {
        const float SMOOTH = 1e-6f;
        float dice    = (2.f * bi + SMOOTH) / (bu + SMOOTH);
        float chamfer = bc0 / (float)N + bc1 / (float)M;
        out[0] = 0.5f * (1.f - dice) + 0.5f * chamfer;
    }
}

extern "C" void kernel_launch(void* const* d_in, const int* in_sizes, int n_in,
                              void* d_out, int out_size, void* d_ws, size_t ws_size,
                              hipStream_t stream) {
    const float*  pred = (const float*)d_in[0];
    const float*  targ = (const float*)d_in[1];
    const float2* pp   = (const float2*)d_in[2];
    const float2* tp   = (const float2*)d_in[3];
    int n = in_sizes[0];
    int N = in_sizes[2] / 2;
    int M = in_sizes[3] / 2;
    float* out = (float*)d_out;

    int npm  = N > M ? N : M;
    int nch0 = (M + TCH - 1) / TCH;
    int nch1 = (N + TCH - 1) / TCH;
    int chm  = nch0 > nch1 ? nch0 : nch1;
    int gxp  = (npm + PTS * 256 - 1) / (PTS * 256);

    // ws layout: pm | inter_p | uni_p | bsum | counter
    char*  ws      = (char*)d_ws;
    float* pm      = (float*)ws;
    size_t pm_bytes = (size_t)2 * chm * npm * sizeof(float);
    size_t off     = (pm_bytes + 255) & ~(size_t)255;
    float* inter_p = (float*)(ws + off);
    float* uni_p   = inter_p + DICE_BLOCKS;
    float* bsum    = uni_p + DICE_BLOCKS;
    unsigned int* counter = (unsigned int*)(bsum + 2 * SCAN_PER_DIR);

    int cham_blocks = 2 * gxp * chm;
    cham_partials<<<cham_blocks, 256, 0, stream>>>(pp, tp, N, M, pm, npm, chm,
                                                   gxp, counter);

    int nblk_fin = 2 * SCAN_PER_DIR + DICE_BLOCKS;
    finalize_all<<<nblk_fin, 256, 0, stream>>>(
        (const float4*)pred, (const float4*)targ, n / 4,
        pm, npm, chm, N, M, nch0, nch1, pp, tp,
        inter_p, uni_p, bsum, counter, nblk_fin, out);
}

// Round 13
// 27.870 us; speedup vs baseline: 2.8647x; 1.6186x over previous
//
#include <hip/hip_runtime.h>
#include <math.h>

#define INFBITS 0x7F800000u
#define TCH 128          // chamfer LDS tile (R9-best)
#define PTS 8            // query points per thread (R9-best)
#define DICE_BLOCKS 512

typedef float v2f __attribute__((ext_vector_type(2)));

// ---------- block-wide sum (blockDim.x == 256, 4 waves) ----------
__device__ __forceinline__ float block_sum256(float v) {
#pragma unroll
    for (int o = 32; o > 0; o >>= 1) v += __shfl_down(v, o, 64);
    __shared__ float sb[4];
    if ((threadIdx.x & 63) == 0) sb[threadIdx.x >> 6] = v;
    __syncthreads();
    float r = sb[0] + sb[1] + sb[2] + sb[3];
    __syncthreads();
    return r;
}

// ---------- K1: fused dice partials + chamfer partial mins ----------
// Structure = R9 (best, 28.6us). R13 lever: PACKED f32 math in the chamfer
// inner loop. LDS holds j-pairs pre-swizzled as {b0x,b1x,b0y,b1y}; per
// (i, j-pair) the compiler emits 2 v_pk_fma_f32 + 1 v_min3_f32 -> 26
// VALU insts per 2 targets vs R9's 50. nx2/ny2 are v2f splats (+16 VGPR
// over R11's measured 32 -> still <=64, 8 waves/SIMD preserved).
__global__ void __launch_bounds__(256) fused_partials(
        const float4* __restrict__ p4, const float4* __restrict__ t4, int n4,
        float* __restrict__ inter_p, float* __restrict__ uni_p,
        const float2* __restrict__ P, const float2* __restrict__ T,
        int N, int M, float* __restrict__ pm, int npm, int chm, int gxp,
        unsigned int* __restrict__ counter) {
    int bid = blockIdx.x;
    if (bid == 0 && threadIdx.x == 0) *counter = 0u;   // reset K2's semaphore

    if (bid < DICE_BLOCKS) {
        float inter = 0.f, uni = 0.f;
#pragma unroll 2
        for (int i = bid * 256 + threadIdx.x; i < n4; i += DICE_BLOCKS * 256) {
            float4 p = p4[i];
            float4 t = t4[i];
            float s;
            s = __fdividef(1.f, 1.f + __expf(-p.x)); inter = fmaf(s, t.x, inter); uni += s + t.x;
            s = __fdividef(1.f, 1.f + __expf(-p.y)); inter = fmaf(s, t.y, inter); uni += s + t.y;
            s = __fdividef(1.f, 1.f + __expf(-p.z)); inter = fmaf(s, t.z, inter); uni += s + t.z;
            s = __fdividef(1.f, 1.f + __expf(-p.w)); inter = fmaf(s, t.w, inter); uni += s + t.w;
        }
        float bi = block_sum256(inter);
        float bu = block_sum256(uni);
        if (threadIdx.x == 0) { inter_p[bid] = bi; uni_p[bid] = bu; }
        return;
    }

    // ---- chamfer partials ----
    int cb      = bid - DICE_BLOCKS;
    int per_dir = gxp * chm;
    int dir     = cb / per_dir;
    int rem     = cb - dir * per_dir;
    int cy      = rem / gxp;          // target chunk
    int cx      = rem - cy * gxp;     // query-point group
    const float2* A = dir ? T : P;
    const float2* B = dir ? P : T;
    int nA = dir ? M : N;
    int nB = dir ? N : M;

    int tb = cy * TCH;
    if (tb >= nB) return;             // uniform per block

    // LDS: one float4 per j-PAIR, swizzled {b0x, b1x, b0y, b1y}
    __shared__ __align__(16) float4 qs[TCH / 2];
    int t = threadIdx.x;
    if (t < TCH / 2) {
        int j0 = tb + 2 * t;
        float4 r = make_float4(1e18f, 1e18f, 1e18f, 1e18f);  // pad never wins
        if (j0 + 1 < nB) {
            // B is consecutive float2 -> one coalesced float4 load
            float4 b = *(const float4*)&B[j0];               // {b0x,b0y,b1x,b1y}
            r = make_float4(b.x, b.z, b.y, b.w);             // swizzle to SoA pair
        } else if (j0 < nB) {
            float2 b = B[j0];
            r = make_float4(b.x, 1e18f, b.y, 1e18f);
        }
        qs[t] = r;
    }
    __syncthreads();

    int abase = cx * (PTS * 256);
    v2f nx2[PTS], ny2[PTS];
    float mn[PTS];
#pragma unroll
    for (int i = 0; i < PTS; ++i) {
        int p = abase + i * 256 + t;
        float nx = 0.f, ny = 0.f;
        mn[i] = __uint_as_float(INFBITS);
        if (p < nA) {
            float2 a = A[p];
            nx = -2.f * a.x;
            ny = -2.f * a.y;
        }
        nx2[i] = (v2f){nx, nx};
        ny2[i] = (v2f){ny, ny};
    }

    // packed inner loop: per j-pair, S = X*X + Y*Y (2 pk insts), then per i:
    // D = nx2*X + (ny2*Y + S) (2 v_pk_fma_f32) and v_min3_f32 fold.
#pragma unroll 4
    for (int jp = 0; jp < TCH / 2; ++jp) {
        float4 q = qs[jp];                 // {b0x,b1x,b0y,b1y}
        v2f X = (v2f){q.x, q.y};
        v2f Y = (v2f){q.z, q.w};
        v2f S = X * X + Y * Y;
#pragma unroll
        for (int i = 0; i < PTS; ++i) {
            v2f D = nx2[i] * X + (ny2[i] * Y + S);
            mn[i] = fminf(fminf(mn[i], D.x), D.y);
        }
    }

    float* dstc = pm + ((size_t)dir * chm + cy) * npm;
#pragma unroll
    for (int i = 0; i < PTS; ++i) {
        int p = abase + i * 256 + t;
        if (p < nA) dstc[p] = mn[i];
    }
}

// ---------- K2: fused finalize ----------
// grid = 2*gxf blocks; per-point min across chunks, + ||a||^2, block sum;
// last block combines dice partials + chamfer block sums into the scalar.
__global__ void __launch_bounds__(256) finalize_all(
        const float* __restrict__ pm, int npm, int chm,
        int N, int M, int nch0, int nch1,
        const float2* __restrict__ P, const float2* __restrict__ T,
        const float* __restrict__ inter_p, const float* __restrict__ uni_p,
        float* __restrict__ bsum, unsigned int* __restrict__ counter,
        int gxf, float* __restrict__ out) {
    int blk = blockIdx.x;
    int dir = blk / gxf;
    int bx  = blk - dir * gxf;
    int nA  = dir ? M : N;
    int nch = dir ? nch1 : nch0;
    const float2* A = dir ? T : P;

    int p = bx * 256 + threadIdx.x;
    float v = 0.f;
    if (p < nA) {
        const float* src = pm + (size_t)dir * chm * npm + p;
        float m = __uint_as_float(INFBITS);
#pragma unroll 16
        for (int c = 0; c < nch; ++c) m = fminf(m, src[(size_t)c * npm]);
        float2 a = A[p];
        v = m + fmaf(a.x, a.x, a.y * a.y);   // add the deferred ||a||^2
    }
    float s = block_sum256(v);

    __shared__ int is_last;
    if (threadIdx.x == 0) {
        bsum[blk] = s;
        __threadfence();
        unsigned int old = atomicAdd(counter, 1u);
        is_last = (old == (unsigned)(2 * gxf - 1));
    }
    __syncthreads();
    if (!is_last) return;
    __threadfence();

    float inter = 0.f, uni = 0.f, c0 = 0.f, c1 = 0.f;
    for (int i = threadIdx.x; i < DICE_BLOCKS; i += 256) {
        inter += inter_p[i];
        uni   += uni_p[i];
    }
    const volatile float* vb = bsum;
    for (int i = threadIdx.x; i < gxf; i += 256) {
        c0 += vb[i];
        c1 += vb[gxf + i];
    }
    float bi  = block_sum256(inter);
    float bu  = block_sum256(uni);
    float bc0 = block_sum256(c0);
    float bc1 = block_sum256(c1);
    if (threadIdx.x == 0) {
        const float SMOOTH = 1e-6f;
        float dice    = (2.f * bi + SMOOTH) / (bu + SMOOTH);
        float chamfer = bc0 / (float)N + bc1 / (float)M;
        out[0] = 0.5f * (1.f - dice) + 0.5f * chamfer;
    }
}

extern "C" void kernel_launch(void* const* d_in, const int* in_sizes, int n_in,
                              void* d_out, int out_size, void* d_ws, size_t ws_size,
                              hipStream_t stream) {
    const float*  pred = (const float*)d_in[0];
    const float*  targ = (const float*)d_in[1];
    const float2* pp   = (const float2*)d_in[2];
    const float2* tp   = (const float2*)d_in[3];
    int n = in_sizes[0];
    int N = in_sizes[2] / 2;
    int M = in_sizes[3] / 2;
    float* out = (float*)d_out;

    int npm  = N > M ? N : M;
    int nch0 = (M + TCH - 1) / TCH;
    int nch1 = (N + TCH - 1) / TCH;
    int chm  = nch0 > nch1 ? nch0 : nch1;
    int gxp  = (npm + PTS * 256 - 1) / (PTS * 256);
    int gxf  = (npm + 255) / 256;

    // ws layout: pm | inter_p | uni_p | bsum | counter
    char*  ws      = (char*)d_ws;
    float* pm      = (float*)ws;
    size_t pm_bytes = (size_t)2 * chm * npm * sizeof(float);
    size_t off     = (pm_bytes + 255) & ~(size_t)255;
    float* inter_p = (float*)(ws + off);
    float* uni_p   = inter_p + DICE_BLOCKS;
    float* bsum    = uni_p + DICE_BLOCKS;
    unsigned int* counter = (unsigned int*)(bsum + 2 * gxf);

    int cham_blocks = 2 * gxp * chm;
    fused_partials<<<DICE_BLOCKS + cham_blocks, 256, 0, stream>>>(
        (const float4*)pred, (const float4*)targ, n / 4,
        inter_p, uni_p, pp, tp, N, M, pm, npm, chm, gxp, counter);

    finalize_all<<<2 * gxf, 256, 0, stream>>>(pm, npm, chm, N, M, nch0, nch1,
                                              pp, tp, inter_p, uni_p, bsum,
                                              counter, gxf, out);
}